// Round 1
// baseline (2135.132 us; speedup 1.0000x reference)
//
#include <hip/hip_runtime.h>

#define LEAKY(v) fmaxf((v), 0.01f * (v))

// dst = src^T for a 128x128 fp32 matrix
__global__ __launch_bounds__(128) void transpose128(const float* __restrict__ src,
                                                    float* __restrict__ dst) {
    int r = blockIdx.x;   // 0..127
    int c = threadIdx.x;  // 0..127
    dst[(size_t)c * 128 + r] = src[(size_t)r * 128 + c];
}

// out[r][:] = h[r][:] @ W + b, with WT = W^T so each output column's weights
// are a contiguous, wave-uniform row (scalar-cacheable loads).
__global__ __launch_bounds__(64) void node_linear(const float* __restrict__ h,
                                                  const float* __restrict__ WT,
                                                  const float* __restrict__ b,
                                                  float* __restrict__ out, int N) {
    int r = blockIdx.x * 64 + threadIdx.x;
    if (r >= N) return;
    const float4* hp = (const float4*)(h + (size_t)r * 128);
    float x[128];
#pragma unroll
    for (int q = 0; q < 32; ++q) {
        float4 v = hp[q];
        x[4 * q + 0] = v.x; x[4 * q + 1] = v.y;
        x[4 * q + 2] = v.z; x[4 * q + 3] = v.w;
    }
    float* op = out + (size_t)r * 128;
    for (int c = 0; c < 128; ++c) {
        const float* w = WT + c * 128;   // wave-uniform address -> s_load
        float a0 = 0.f, a1 = 0.f, a2 = 0.f, a3 = 0.f;
#pragma unroll
        for (int k = 0; k < 128; k += 4) {
            a0 += x[k + 0] * w[k + 0];
            a1 += x[k + 1] * w[k + 1];
            a2 += x[k + 2] * w[k + 2];
            a3 += x[k + 3] * w[k + 3];
        }
        op[c] = (a0 + a1) + (a2 + a3) + b[c];
    }
}

// Per edge: x = leaky(u_f[src] + i_f[dst]); y = leaky(x@W1+b1); out = leaky(y@W2+b2)
// y never materialized: z += leaky(y_j) * W2[j] fused into the j-loop.
__global__ __launch_bounds__(64) void edge_kernel(const float* __restrict__ u_f,
                                                  const float* __restrict__ i_f,
                                                  const int* __restrict__ src,
                                                  const int* __restrict__ dst,
                                                  const float* __restrict__ W1T,
                                                  const float* __restrict__ b1,
                                                  const float* __restrict__ W2,
                                                  const float* __restrict__ b2,
                                                  float* __restrict__ out, int E) {
    int e = blockIdx.x * 64 + threadIdx.x;
    if (e >= E) return;
    const float4* up = (const float4*)(u_f + (size_t)src[e] * 128);
    const float4* ip = (const float4*)(i_f + (size_t)dst[e] * 128);
    float x[128];
#pragma unroll
    for (int q = 0; q < 32; ++q) {
        float4 a = up[q];
        float4 c = ip[q];
        float v0 = a.x + c.x, v1 = a.y + c.y, v2 = a.z + c.z, v3 = a.w + c.w;
        x[4 * q + 0] = LEAKY(v0);
        x[4 * q + 1] = LEAKY(v1);
        x[4 * q + 2] = LEAKY(v2);
        x[4 * q + 3] = LEAKY(v3);
    }
    float z = 0.f;
    for (int j = 0; j < 128; ++j) {
        const float* w = W1T + j * 128;  // wave-uniform -> scalar loads, K$-hot
        float a0 = 0.f, a1 = 0.f, a2 = 0.f, a3 = 0.f;
#pragma unroll
        for (int k = 0; k < 128; k += 4) {
            a0 += x[k + 0] * w[k + 0];
            a1 += x[k + 1] * w[k + 1];
            a2 += x[k + 2] * w[k + 2];
            a3 += x[k + 3] * w[k + 3];
        }
        float y = (a0 + a1) + (a2 + a3) + b1[j];
        z += LEAKY(y) * W2[j];
    }
    z += b2[0];
    out[e] = LEAKY(z);
}

extern "C" void kernel_launch(void* const* d_in, const int* in_sizes, int n_in,
                              void* d_out, int out_size, void* d_ws, size_t ws_size,
                              hipStream_t stream) {
    const float* h_user  = (const float*)d_in[0];
    const float* h_item  = (const float*)d_in[1];
    const int*   src_idx = (const int*)d_in[2];
    const int*   dst_idx = (const int*)d_in[3];
    const float* W_left  = (const float*)d_in[4];
    const float* b_left  = (const float*)d_in[5];
    const float* W_right = (const float*)d_in[6];
    const float* b_right = (const float*)d_in[7];
    const float* W1      = (const float*)d_in[8];
    const float* b1      = (const float*)d_in[9];
    const float* W2      = (const float*)d_in[10];
    const float* b2      = (const float*)d_in[11];
    float* out = (float*)d_out;

    int N_U = in_sizes[0] / 128;
    int N_I = in_sizes[1] / 128;
    int E   = in_sizes[2];

    // Workspace layout (floats):
    //   [0 .. 16384)        W_left^T
    //   [16384 .. 32768)    W_right^T
    //   [32768 .. 49152)    W1^T
    //   [49152 .. +N_U*128) u_f
    //   [ ..   .. +N_I*128) i_f
    float* wsf = (float*)d_ws;
    float* WLT = wsf;
    float* WRT = wsf + 16384;
    float* W1T = wsf + 32768;
    float* u_f = wsf + 49152;
    float* i_f = u_f + (size_t)N_U * 128;

    transpose128<<<128, 128, 0, stream>>>(W_left, WLT);
    transpose128<<<128, 128, 0, stream>>>(W_right, WRT);
    transpose128<<<128, 128, 0, stream>>>(W1, W1T);

    node_linear<<<(N_U + 63) / 64, 64, 0, stream>>>(h_user, WLT, b_left, u_f, N_U);
    node_linear<<<(N_I + 63) / 64, 64, 0, stream>>>(h_item, WRT, b_right, i_f, N_I);

    edge_kernel<<<(E + 63) / 64, 64, 0, stream>>>(u_f, i_f, src_idx, dst_idx,
                                                  W1T, b1, W2, b2, out, E);
}

// Round 2
// 575.425 us; speedup vs baseline: 3.7105x; 3.7105x over previous
//
#include <hip/hip_runtime.h>

typedef __attribute__((ext_vector_type(8))) short bf16x8;
typedef __attribute__((ext_vector_type(4))) float f32x4;

__device__ __forceinline__ float leaky(float v) { return fmaxf(v, 0.01f * v); }

__device__ __forceinline__ unsigned int pk_bf16(float a, float b) {
    unsigned int ua = __float_as_uint(a);
    ua = (ua + 0x7FFFu + ((ua >> 16) & 1u)) >> 16;
    unsigned int ub = __float_as_uint(b);
    ub = (ub + 0x7FFFu + ((ub >> 16) & 1u)) >> 16;
    return ua | (ub << 16);
}

// Wb[n][k] = bf16(W1[k][n])  (B^T layout for MFMA B-fragments)
__global__ __launch_bounds__(128) void prep_wb(const float* __restrict__ W1,
                                               unsigned short* __restrict__ Wb) {
    int k = blockIdx.x;
    int n = threadIdx.x;
    unsigned int u = __float_as_uint(W1[k * 128 + n]);
    u = (u + 0x7FFFu + ((u >> 16) & 1u)) >> 16;
    Wb[n * 128 + k] = (unsigned short)u;
}

// out[r][:] = h[r][:] @ W + b  (fp32, register-pressure-free)
// block = 256 threads = 16 rows x 16 col-chunks of 8
__global__ __launch_bounds__(256, 4) void node_linear(const float* __restrict__ h,
                                                      const float* __restrict__ W,
                                                      const float* __restrict__ b,
                                                      float* __restrict__ out, int N) {
    __shared__ float xs[16 * 132];  // pitch 132 to soften store conflicts
    int t = threadIdx.x;
    int r0 = blockIdx.x * 16;
    int s = t & 15;   // col-chunk / stage segment
    int r = t >> 4;   // row 0..15

    {
        int row = min(r0 + r, N - 1);
        const f32x4* hp = (const f32x4*)(h + (size_t)row * 128);
        f32x4 x0 = hp[2 * s];
        f32x4 x1 = hp[2 * s + 1];
        f32x4* dp = (f32x4*)(xs + r * 132 + 8 * s);
        dp[0] = x0;
        dp[1] = x1;
    }
    __syncthreads();

    float y0 = 0.f, y1 = 0.f, y2 = 0.f, y3 = 0.f;
    float y4 = 0.f, y5 = 0.f, y6 = 0.f, y7 = 0.f;
    const float* xr = xs + r * 132;
#pragma unroll 8
    for (int k4 = 0; k4 < 128; k4 += 4) {
        f32x4 xv = *(const f32x4*)(xr + k4);
#pragma unroll
        for (int kk = 0; kk < 4; ++kk) {
            float xk = xv[kk];
            const f32x4* wr = (const f32x4*)(W + (k4 + kk) * 128 + 8 * s);
            f32x4 w0 = wr[0];
            f32x4 w1 = wr[1];
            y0 += xk * w0.x; y1 += xk * w0.y; y2 += xk * w0.z; y3 += xk * w0.w;
            y4 += xk * w1.x; y5 += xk * w1.y; y6 += xk * w1.z; y7 += xk * w1.w;
        }
    }
    int row = r0 + r;
    if (row < N) {
        const f32x4* bp = (const f32x4*)(b + 8 * s);
        f32x4 b0 = bp[0], b1v = bp[1];
        f32x4 o0 = {y0 + b0.x, y1 + b0.y, y2 + b0.z, y3 + b0.w};
        f32x4 o1 = {y4 + b1v.x, y5 + b1v.y, y6 + b1v.z, y7 + b1v.w};
        f32x4* op = (f32x4*)(out + (size_t)row * 128 + 8 * s);
        op[0] = o0;
        op[1] = o1;
    }
}

// Per 128-edge tile: gather+add+leaky -> LDS bf16 tile -> MFMA x@W1 -> fused
// leaky/bias/W2 epilogue -> out.
#define TE 128
#define PITCH 136  // bf16 elems per LDS row (128 + 8 pad -> 2-way-free ds_read_b128)

__global__ __launch_bounds__(256, 4) void edge_kernel(
    const float* __restrict__ u_f, const float* __restrict__ i_f,
    const int* __restrict__ src, const int* __restrict__ dst,
    const unsigned short* __restrict__ Wb,  // bf16 [n][k]
    const float* __restrict__ b1, const float* __restrict__ W2,
    const float* __restrict__ b2, float* __restrict__ out, int E) {
    __shared__ unsigned short xt[TE * PITCH];
    int t = threadIdx.x;
    int e0 = blockIdx.x * TE;

    // ---- stage: 16 threads per edge, 8 passes of 16 edges ----
    int s = t & 15;
    int el0 = t >> 4;
#pragma unroll
    for (int pass = 0; pass < 8; ++pass) {
        int el = pass * 16 + el0;
        int ec = min(e0 + el, E - 1);
        const f32x4* up = (const f32x4*)(u_f + (size_t)src[ec] * 128);
        const f32x4* ip = (const f32x4*)(i_f + (size_t)dst[ec] * 128);
        f32x4 a0 = up[s];
        f32x4 a1 = up[s + 16];
        f32x4 c0 = ip[s];
        f32x4 c1 = ip[s + 16];
        f32x4 s0 = {leaky(a0.x + c0.x), leaky(a0.y + c0.y),
                    leaky(a0.z + c0.z), leaky(a0.w + c0.w)};
        f32x4 s1 = {leaky(a1.x + c1.x), leaky(a1.y + c1.y),
                    leaky(a1.z + c1.z), leaky(a1.w + c1.w)};
        unsigned int* row = (unsigned int*)(xt + el * PITCH);
        // k in [4s,4s+4) and [64+4s, 64+4s+4)
        row[2 * s]      = pk_bf16(s0.x, s0.y);
        row[2 * s + 1]  = pk_bf16(s0.z, s0.w);
        row[32 + 2 * s]     = pk_bf16(s1.x, s1.y);
        row[32 + 2 * s + 1] = pk_bf16(s1.z, s1.w);
    }
    __syncthreads();

    // ---- MFMA: wave w computes rows [32w,32w+32) x cols [0,128) ----
    int wave = t >> 6;
    int lane = t & 63;
    int m0 = wave * 32;
    int col = lane & 15;
    int quad = lane >> 4;

    f32x4 acc[2][8];
#pragma unroll
    for (int mt = 0; mt < 2; ++mt)
#pragma unroll
        for (int nt = 0; nt < 8; ++nt) acc[mt][nt] = (f32x4){0.f, 0.f, 0.f, 0.f};

#pragma unroll
    for (int k0 = 0; k0 < 128; k0 += 32) {
        bf16x8 afr[2];
#pragma unroll
        for (int mt = 0; mt < 2; ++mt)
            afr[mt] = *(const bf16x8*)(xt + (m0 + mt * 16 + col) * PITCH + k0 + quad * 8);
#pragma unroll
        for (int nt = 0; nt < 8; ++nt) {
            bf16x8 bfr = *(const bf16x8*)(Wb + (nt * 16 + col) * 128 + k0 + quad * 8);
            acc[0][nt] = __builtin_amdgcn_mfma_f32_16x16x32_bf16(afr[0], bfr, acc[0][nt], 0, 0, 0);
            acc[1][nt] = __builtin_amdgcn_mfma_f32_16x16x32_bf16(afr[1], bfr, acc[1][nt], 0, 0, 0);
        }
    }

    // ---- epilogue: z[m] = sum_n leaky(y+b1[n])*W2[n]; out = leaky(z+b2) ----
    float p[2][4];
#pragma unroll
    for (int mt = 0; mt < 2; ++mt)
#pragma unroll
        for (int rr = 0; rr < 4; ++rr) p[mt][rr] = 0.f;

#pragma unroll
    for (int nt = 0; nt < 8; ++nt) {
        int n = nt * 16 + col;
        float bb = b1[n];
        float ww = W2[n];
#pragma unroll
        for (int mt = 0; mt < 2; ++mt)
#pragma unroll
            for (int rr = 0; rr < 4; ++rr) {
                float y = acc[mt][nt][rr] + bb;
                p[mt][rr] += leaky(y) * ww;
            }
    }
#pragma unroll
    for (int off = 1; off < 16; off <<= 1)
#pragma unroll
        for (int mt = 0; mt < 2; ++mt)
#pragma unroll
            for (int rr = 0; rr < 4; ++rr)
                p[mt][rr] += __shfl_xor(p[mt][rr], off, 64);

    if (col == 0) {
        float bias2 = b2[0];
#pragma unroll
        for (int mt = 0; mt < 2; ++mt)
#pragma unroll
            for (int rr = 0; rr < 4; ++rr) {
                int e = e0 + m0 + mt * 16 + quad * 4 + rr;
                if (e < E) out[e] = leaky(p[mt][rr] + bias2);
            }
    }
}

extern "C" void kernel_launch(void* const* d_in, const int* in_sizes, int n_in,
                              void* d_out, int out_size, void* d_ws, size_t ws_size,
                              hipStream_t stream) {
    const float* h_user  = (const float*)d_in[0];
    const float* h_item  = (const float*)d_in[1];
    const int*   src_idx = (const int*)d_in[2];
    const int*   dst_idx = (const int*)d_in[3];
    const float* W_left  = (const float*)d_in[4];
    const float* b_left  = (const float*)d_in[5];
    const float* W_right = (const float*)d_in[6];
    const float* b_right = (const float*)d_in[7];
    const float* W1      = (const float*)d_in[8];
    const float* b1      = (const float*)d_in[9];
    const float* W2      = (const float*)d_in[10];
    const float* b2      = (const float*)d_in[11];
    float* out = (float*)d_out;

    int N_U = in_sizes[0] / 128;
    int N_I = in_sizes[1] / 128;
    int E   = in_sizes[2];

    // Workspace: [Wb bf16 32KB (pad to 64KB)] [u_f fp32] [i_f fp32]
    unsigned short* Wb = (unsigned short*)d_ws;
    float* u_f = (float*)((char*)d_ws + 65536);
    float* i_f = u_f + (size_t)N_U * 128;

    prep_wb<<<128, 128, 0, stream>>>(W1, Wb);

    node_linear<<<(N_U + 15) / 16, 256, 0, stream>>>(h_user, W_left, b_left, u_f, N_U);
    node_linear<<<(N_I + 15) / 16, 256, 0, stream>>>(h_item, W_right, b_right, i_f, N_I);

    edge_kernel<<<(E + TE - 1) / TE, 256, 0, stream>>>(u_f, i_f, src_idx, dst_idx,
                                                       Wb, b1, W2, b2, out, E);
}

// Round 3
// 346.095 us; speedup vs baseline: 6.1692x; 1.6626x over previous
//
#include <hip/hip_runtime.h>

typedef __attribute__((ext_vector_type(8))) short bf16x8;
typedef __attribute__((ext_vector_type(4))) float f32x4;

__device__ __forceinline__ float leaky(float v) { return fmaxf(v, 0.01f * v); }

__device__ __forceinline__ unsigned int pk_bf16(float a, float b) {
    unsigned int ua = __float_as_uint(a);
    ua = (ua + 0x7FFFu + ((ua >> 16) & 1u)) >> 16;
    unsigned int ub = __float_as_uint(b);
    ub = (ub + 0x7FFFu + ((ub >> 16) & 1u)) >> 16;
    return ua | (ub << 16);
}

// Wb[n][k] = bf16(W[k][n])  (B^T layout for MFMA B-fragments)
__global__ __launch_bounds__(128) void prep_wb(const float* __restrict__ W,
                                               unsigned short* __restrict__ Wb) {
    int k = blockIdx.x;
    int n = threadIdx.x;
    unsigned int u = __float_as_uint(W[k * 128 + n]);
    u = (u + 0x7FFFu + ((u >> 16) & 1u)) >> 16;
    Wb[n * 128 + k] = (unsigned short)u;
}

#define PITCH 136  // bf16 elems per LDS row

// out[r][:] = h[r][:] @ W + b via bf16 MFMA, fp32 accumulate.
// block = 256 threads = 4 waves; 128 rows/block; wave w: rows [32w, 32w+32).
__global__ __launch_bounds__(256, 4) void node_mfma(const float* __restrict__ h,
                                                    const unsigned short* __restrict__ Wb,
                                                    const float* __restrict__ b,
                                                    float* __restrict__ out, int N) {
    __shared__ unsigned short xt[128 * PITCH];
    int t = threadIdx.x;
    int r0 = blockIdx.x * 128;
    int s = t & 15;
    int el0 = t >> 4;
#pragma unroll
    for (int pass = 0; pass < 8; ++pass) {
        int el = pass * 16 + el0;
        int row = min(r0 + el, N - 1);
        const f32x4* hp = (const f32x4*)(h + (size_t)row * 128);
        f32x4 a0 = hp[s];
        f32x4 a1 = hp[s + 16];
        unsigned int* rp = (unsigned int*)(xt + el * PITCH);
        rp[2 * s]          = pk_bf16(a0.x, a0.y);
        rp[2 * s + 1]      = pk_bf16(a0.z, a0.w);
        rp[32 + 2 * s]     = pk_bf16(a1.x, a1.y);
        rp[32 + 2 * s + 1] = pk_bf16(a1.z, a1.w);
    }
    __syncthreads();

    int wave = t >> 6;
    int lane = t & 63;
    int m0 = wave * 32;
    int col = lane & 15;
    int quad = lane >> 4;

    f32x4 acc[2][8];
#pragma unroll
    for (int mt = 0; mt < 2; ++mt)
#pragma unroll
        for (int nt = 0; nt < 8; ++nt) acc[mt][nt] = (f32x4){0.f, 0.f, 0.f, 0.f};

#pragma unroll
    for (int k0 = 0; k0 < 128; k0 += 32) {
        bf16x8 afr[2];
#pragma unroll
        for (int mt = 0; mt < 2; ++mt)
            afr[mt] = *(const bf16x8*)(xt + (m0 + mt * 16 + col) * PITCH + k0 + quad * 8);
#pragma unroll
        for (int nt = 0; nt < 8; ++nt) {
            bf16x8 bfr = *(const bf16x8*)(Wb + (nt * 16 + col) * 128 + k0 + quad * 8);
            acc[0][nt] = __builtin_amdgcn_mfma_f32_16x16x32_bf16(afr[0], bfr, acc[0][nt], 0, 0, 0);
            acc[1][nt] = __builtin_amdgcn_mfma_f32_16x16x32_bf16(afr[1], bfr, acc[1][nt], 0, 0, 0);
        }
    }

#pragma unroll
    for (int nt = 0; nt < 8; ++nt) {
        float bb = b[nt * 16 + col];
#pragma unroll
        for (int mt = 0; mt < 2; ++mt)
#pragma unroll
            for (int rr = 0; rr < 4; ++rr) {
                int row = r0 + m0 + mt * 16 + quad * 4 + rr;
                if (row < N) out[(size_t)row * 128 + nt * 16 + col] = acc[mt][nt][rr] + bb;
            }
    }
}

// Per 128-edge tile: gather+add+leaky -> LDS bf16 tile -> MFMA x@W1 -> fused
// leaky/bias/W2 epilogue -> out.
#define TE 128

__global__ __launch_bounds__(256, 4) void edge_kernel(
    const float* __restrict__ u_f, const float* __restrict__ i_f,
    const int* __restrict__ src, const int* __restrict__ dst,
    const unsigned short* __restrict__ Wb,  // bf16 [n][k]
    const float* __restrict__ b1, const float* __restrict__ W2,
    const float* __restrict__ b2, float* __restrict__ out, int E) {
    __shared__ unsigned short xt[TE * PITCH];
    int t = threadIdx.x;
    int e0 = blockIdx.x * TE;

    // ---- stage: 16 threads per edge, 8 passes of 16 edges ----
    int s = t & 15;
    int el0 = t >> 4;
#pragma unroll
    for (int pass = 0; pass < 8; ++pass) {
        int el = pass * 16 + el0;
        int ec = min(e0 + el, E - 1);
        const f32x4* up = (const f32x4*)(u_f + (size_t)src[ec] * 128);
        const f32x4* ip = (const f32x4*)(i_f + (size_t)dst[ec] * 128);
        f32x4 a0 = up[s];
        f32x4 a1 = up[s + 16];
        f32x4 c0 = ip[s];
        f32x4 c1 = ip[s + 16];
        f32x4 s0 = {leaky(a0.x + c0.x), leaky(a0.y + c0.y),
                    leaky(a0.z + c0.z), leaky(a0.w + c0.w)};
        f32x4 s1 = {leaky(a1.x + c1.x), leaky(a1.y + c1.y),
                    leaky(a1.z + c1.z), leaky(a1.w + c1.w)};
        unsigned int* row = (unsigned int*)(xt + el * PITCH);
        row[2 * s]          = pk_bf16(s0.x, s0.y);
        row[2 * s + 1]      = pk_bf16(s0.z, s0.w);
        row[32 + 2 * s]     = pk_bf16(s1.x, s1.y);
        row[32 + 2 * s + 1] = pk_bf16(s1.z, s1.w);
    }
    __syncthreads();

    // ---- MFMA: wave w computes rows [32w,32w+32) x cols [0,128) ----
    int wave = t >> 6;
    int lane = t & 63;
    int m0 = wave * 32;
    int col = lane & 15;
    int quad = lane >> 4;

    f32x4 acc[2][8];
#pragma unroll
    for (int mt = 0; mt < 2; ++mt)
#pragma unroll
        for (int nt = 0; nt < 8; ++nt) acc[mt][nt] = (f32x4){0.f, 0.f, 0.f, 0.f};

#pragma unroll
    for (int k0 = 0; k0 < 128; k0 += 32) {
        bf16x8 afr[2];
#pragma unroll
        for (int mt = 0; mt < 2; ++mt)
            afr[mt] = *(const bf16x8*)(xt + (m0 + mt * 16 + col) * PITCH + k0 + quad * 8);
#pragma unroll
        for (int nt = 0; nt < 8; ++nt) {
            bf16x8 bfr = *(const bf16x8*)(Wb + (nt * 16 + col) * 128 + k0 + quad * 8);
            acc[0][nt] = __builtin_amdgcn_mfma_f32_16x16x32_bf16(afr[0], bfr, acc[0][nt], 0, 0, 0);
            acc[1][nt] = __builtin_amdgcn_mfma_f32_16x16x32_bf16(afr[1], bfr, acc[1][nt], 0, 0, 0);
        }
    }

    // ---- epilogue: z[m] = sum_n leaky(y+b1[n])*W2[n]; out = leaky(z+b2) ----
    float p[2][4];
#pragma unroll
    for (int mt = 0; mt < 2; ++mt)
#pragma unroll
        for (int rr = 0; rr < 4; ++rr) p[mt][rr] = 0.f;

#pragma unroll
    for (int nt = 0; nt < 8; ++nt) {
        int n = nt * 16 + col;
        float bb = b1[n];
        float ww = W2[n];
#pragma unroll
        for (int mt = 0; mt < 2; ++mt)
#pragma unroll
            for (int rr = 0; rr < 4; ++rr) {
                float y = acc[mt][nt][rr] + bb;
                p[mt][rr] += leaky(y) * ww;
            }
    }
#pragma unroll
    for (int off = 1; off < 16; off <<= 1)
#pragma unroll
        for (int mt = 0; mt < 2; ++mt)
#pragma unroll
            for (int rr = 0; rr < 4; ++rr)
                p[mt][rr] += __shfl_xor(p[mt][rr], off, 64);

    if (col == 0) {
        float bias2 = b2[0];
#pragma unroll
        for (int mt = 0; mt < 2; ++mt)
#pragma unroll
            for (int rr = 0; rr < 4; ++rr) {
                int e = e0 + m0 + mt * 16 + quad * 4 + rr;
                if (e < E) out[e] = leaky(p[mt][rr] + bias2);
            }
    }
}

extern "C" void kernel_launch(void* const* d_in, const int* in_sizes, int n_in,
                              void* d_out, int out_size, void* d_ws, size_t ws_size,
                              hipStream_t stream) {
    const float* h_user  = (const float*)d_in[0];
    const float* h_item  = (const float*)d_in[1];
    const int*   src_idx = (const int*)d_in[2];
    const int*   dst_idx = (const int*)d_in[3];
    const float* W_left  = (const float*)d_in[4];
    const float* b_left  = (const float*)d_in[5];
    const float* W_right = (const float*)d_in[6];
    const float* b_right = (const float*)d_in[7];
    const float* W1      = (const float*)d_in[8];
    const float* b1      = (const float*)d_in[9];
    const float* W2      = (const float*)d_in[10];
    const float* b2      = (const float*)d_in[11];
    float* out = (float*)d_out;

    int N_U = in_sizes[0] / 128;
    int N_I = in_sizes[1] / 128;
    int E   = in_sizes[2];

    // Workspace: [Wb1 32KB][WLb 32KB][WRb 32KB][pad to 128KB][u_f fp32][i_f fp32]
    unsigned short* Wb1 = (unsigned short*)d_ws;
    unsigned short* WLb = Wb1 + 16384;
    unsigned short* WRb = WLb + 16384;
    float* u_f = (float*)((char*)d_ws + 131072);
    float* i_f = u_f + (size_t)N_U * 128;

    prep_wb<<<128, 128, 0, stream>>>(W1, Wb1);
    prep_wb<<<128, 128, 0, stream>>>(W_left, WLb);
    prep_wb<<<128, 128, 0, stream>>>(W_right, WRb);

    node_mfma<<<(N_U + 127) / 128, 256, 0, stream>>>(h_user, WLb, b_left, u_f, N_U);
    node_mfma<<<(N_I + 127) / 128, 256, 0, stream>>>(h_item, WRb, b_right, i_f, N_I);

    edge_kernel<<<(E + TE - 1) / TE, 256, 0, stream>>>(u_f, i_f, src_idx, dst_idx,
                                                       Wb1, b1, W2, b2, out, E);
}